// Round 10
// baseline (286.093 us; speedup 1.0000x reference)
//
#include <hip/hip_runtime.h>

#define D 256
#define NKEYS 50000
#define KCHUNK 256
#define NCHUNK 196           // 50176 / 256
#define NKPAD (KCHUNK * NCHUNK)
#define BQ 2048
#define NC (NCHUNK * 4)      // 784 candidates/query
#define NCAND 16             // rescored candidates per query
#define DNEG_INF (-1.0e300)

typedef __attribute__((ext_vector_type(8))) __bf16 bf16x8;
typedef __attribute__((ext_vector_type(16))) float f32x16;

// round-to-nearest-even f32 -> bf16 bits
__device__ __forceinline__ unsigned short f2bf(float x) {
  unsigned int u = __float_as_uint(x);
  unsigned int r = (u + 0x7fffu + ((u >> 16) & 1u)) >> 16;
  return (unsigned short)r;
}

// ---------- Kernel 1: q = query @ W^T + b (fp64 accum), L2-normalize ----------
// 256 blocks x 8 query rows (full CU coverage).
__global__ __launch_bounds__(256) void qnorm_kernel(const float* __restrict__ query,
                                                    const float* __restrict__ W,
                                                    const float* __restrict__ b,
                                                    unsigned short* __restrict__ qbf,
                                                    double* __restrict__ q64n) {
  __shared__ __align__(16) float As[8][20];
  __shared__ __align__(16) float Bs[256][20];
  const int tid = threadIdx.x;
  const int qt = tid >> 5;   // 0..7 -> row m0+qt
  const int nt = tid & 31;   // cols nt + 32*j, j<8
  const int m0 = blockIdx.x * 8;

  double acc[8];
#pragma unroll
  for (int j = 0; j < 8; j++) acc[j] = 0.0;

  for (int k0 = 0; k0 < D; k0 += 16) {
    if (tid < 32) {
      int r = tid >> 2, f = tid & 3;
      *(float4*)(&As[r][f * 4]) = *(const float4*)(&query[(m0 + r) * D + k0 + f * 4]);
    }
#pragma unroll
    for (int i = 0; i < 4; i++) {
      int r = (tid >> 2) + 64 * i, f = tid & 3;
      *(float4*)(&Bs[r][f * 4]) = *(const float4*)(&W[r * D + k0 + f * 4]);
    }
    __syncthreads();
#pragma unroll
    for (int kk = 0; kk < 16; kk += 4) {
      float4 af = *(const float4*)(&As[qt][kk]);
#pragma unroll
      for (int j = 0; j < 8; j++) {
        float4 bf = *(const float4*)(&Bs[nt + 32 * j][kk]);
        acc[j] = fma((double)af.x, (double)bf.x, acc[j]);
        acc[j] = fma((double)af.y, (double)bf.y, acc[j]);
        acc[j] = fma((double)af.z, (double)bf.z, acc[j]);
        acc[j] = fma((double)af.w, (double)bf.w, acc[j]);
      }
    }
    __syncthreads();
  }
#pragma unroll
  for (int j = 0; j < 8; j++) acc[j] += (double)b[nt + 32 * j];

  double s = 0.0;
#pragma unroll
  for (int j = 0; j < 8; j++) s = fma(acc[j], acc[j], s);
#pragma unroll
  for (int m = 16; m; m >>= 1) s += __shfl_xor(s, m, 32);
  double den = fmax(sqrt(s), 1e-12);
  int row = m0 + qt;
#pragma unroll
  for (int j = 0; j < 8; j++) {
    double v = acc[j] / den;
    q64n[row * D + nt + 32 * j] = v;
    qbf[row * D + nt + 32 * j] = f2bf((float)v);
  }
}

// ---------- Kernel 2: key prep (+ fused usage copy) ----------
// kbf row r = 512B (256 bf16 dims); elem e' = e ^ ((r&31)<<3)  (byte ^ ((r&31)<<4)).
// Linear global_load_lds of a row block then lands the swizzled tile in LDS.
__global__ __launch_bounds__(256) void kprep_kernel(const float* __restrict__ keys,
                                                    const float* __restrict__ usage,
                                                    double* __restrict__ kinv64,
                                                    unsigned short* __restrict__ kbf,
                                                    float* __restrict__ out_u) {
  int wave = threadIdx.x >> 6, lane = threadIdx.x & 63;
  int r = blockIdx.x * 4 + wave;
  if (r >= NKPAD) return;
  if (lane == 0 && r < NKEYS) out_u[r] = usage[r];
  int e = lane * 4;                    // 4 consecutive elems (low 3 bits intact)
  int e2 = e ^ ((r & 31) << 3);
  unsigned short* dst = kbf + (long long)r * D + e2;
  if (r >= NKEYS) {
    ushort4 z = {0, 0, 0, 0};
    *(ushort4*)dst = z;
    return;
  }
  float4 v = *(const float4*)(&keys[(long long)r * D + e]);
  double s = (double)v.x * v.x + (double)v.y * v.y + (double)v.z * v.z + (double)v.w * v.w;
#pragma unroll
  for (int m = 32; m; m >>= 1) s += __shfl_xor(s, m, 64);
  double inv = 1.0 / fmax(sqrt(s), 1e-12);
  if (lane == 0) kinv64[r] = inv;
  float fi = (float)inv;
  ushort4 o;
  o.x = f2bf(v.x * fi); o.y = f2bf(v.y * fi); o.z = f2bf(v.z * fi); o.w = f2bf(v.w * fi);
  *(ushort4*)dst = o;
}

// ---------- Kernel 3: 32x32x16 bf16 MFMA sim, 8 waves, 128q x 256k per block ----------
// Two key-stages of 128 keys x full 256 dims (64KB LDS each, 512B rows, optimal swizzle).
// Wave w: qg=w>>1 (32 queries), h=w&1 (64-key half of the stage). XCD chunk-affinity grid.
__global__ __launch_bounds__(512, 4) void sim_mfma_kernel(const unsigned short* __restrict__ qbf,
                                                          const unsigned short* __restrict__ kbf,
                                                          unsigned int* __restrict__ cand_p) {
  __shared__ __align__(16) unsigned char klds[128 * 512];   // 64KB
  __shared__ __align__(16) unsigned int mlds[4][32][2][4];  // 4KB pair-merge buffer
  const int bid = blockIdx.x;
  const int k8 = bid & 7;
  const int ii = bid >> 3;            // 0..399
  const int qt = ii & 15;             // 16 q-tiles of 128
  const int chunk = (ii >> 4) * 8 + k8;
  if (chunk >= NCHUNK) return;
  const int n0 = chunk * KCHUNK;
  const int m0 = qt * 128;

  const int tid = threadIdx.x;
  const int w = tid >> 6;
  const int l = tid & 63;
  const int col = l & 31;
  const int hi = l >> 5;
  const int qg = w >> 1;              // 0..3
  const int h = w & 1;
  const int qrow = m0 + qg * 32 + col;

  // resident query B-fragments: kstep ks covers dims ks*16 + hi*8 .. +8
  bf16x8 qf[16];
#pragma unroll
  for (int ks = 0; ks < 16; ks++)
    qf[ks] = *(const bf16x8*)(qbf + (long long)qrow * D + ks * 16 + hi * 8);

  unsigned int s0 = 0u, s1 = 0u, s2 = 0u, s3 = 0u;
  const bool edge = (n0 + KCHUNK > NKEYS);

#pragma unroll 1
  for (int st = 0; st < 2; st++) {
    __syncthreads();  // klds free
    // stage 64KB = rows n0 + st*128 .. +128 (linear copy; swizzle pre-baked)
#pragma unroll
    for (int i = 0; i < 8; i++) {
      int dstbase = (i * 8 + w) * 1024;
      int off = dstbase + l * 16;
      int r_loc = off >> 9;
      const void* src = (const char*)kbf + ((long long)(n0 + st * 128 + r_loc) * 512 + (off & 511));
      __builtin_amdgcn_global_load_lds(src, (void*)(klds + dstbase), 16, 0, 0);
    }
    __syncthreads();  // drain

    f32x16 acc[2];
#pragma unroll
    for (int t = 0; t < 2; t++)
#pragma unroll
      for (int r = 0; r < 16; r++) acc[t][r] = 0.f;

#pragma unroll
    for (int t = 0; t < 2; t++) {
      const int rr = h * 64 + t * 32 + col;
      const int rbase = rr * 512 + hi * 16;
      const int swz = (rr & 31) << 4;
#pragma unroll
      for (int ks = 0; ks < 16; ks++) {
        bf16x8 a = *(const bf16x8*)(klds + ((rbase + ks * 32) ^ swz));
        acc[t] = __builtin_amdgcn_mfma_f32_32x32x16_bf16(a, qf[ks], acc[t], 0, 0, 0);
      }
    }

    // pack + streaming insertion top-4 (slot = st*128 + h*64 + t*32 + subrow)
#pragma unroll
    for (int t = 0; t < 2; t++)
#pragma unroll
      for (int r = 0; r < 16; r++) {
        unsigned int u = __float_as_uint(acc[t][r] + 2.0f);
        int slot = st * 128 + h * 64 + t * 32 + (r & 3) + 8 * (r >> 2) + 4 * hi;
        unsigned int v = (u & 0xFFFFFF00u) | (unsigned)slot;
        if (edge && (n0 + slot >= NKEYS)) v = 0u;
        unsigned int m0v = min(s0, v); s0 = max(s0, v);
        unsigned int m1v = min(s1, m0v); s1 = max(s1, m0v);
        unsigned int m2v = min(s2, m1v); s2 = max(s2, m1v);
        s3 = max(s3, m2v);
      }
  }

  // lane-pair merge (l ^ 32 = same query, disjoint keys): bitonic top-4 + sort-4
  unsigned int b0 = (unsigned int)__shfl_xor((int)s0, 32, 64);
  unsigned int b1 = (unsigned int)__shfl_xor((int)s1, 32, 64);
  unsigned int b2 = (unsigned int)__shfl_xor((int)s2, 32, 64);
  unsigned int b3 = (unsigned int)__shfl_xor((int)s3, 32, 64);
  unsigned int t0 = max(s0, b3), t1 = max(s1, b2), t2 = max(s2, b1), t3 = max(s3, b0);
  unsigned int u0 = max(t0, t2), u2 = min(t0, t2), u1 = max(t1, t3), u3 = min(t1, t3);
  unsigned int w0 = max(u0, u1), w1 = min(u0, u1), w2 = max(u2, u3), w3 = min(u2, u3);

  // cross-wave (key-half) merge via LDS; sorted inputs -> pairwise max
  if (hi == 0) {
    uint4 a = {w0, w1, w2, w3};
    *(uint4*)(&mlds[qg][col][h][0]) = a;
  }
  __syncthreads();
  if (h == 0 && hi == 0) {
    uint4 bb = *(const uint4*)(&mlds[qg][col][1][0]);
    uint4 o = {max(w0, bb.w), max(w1, bb.z), max(w2, bb.y), max(w3, bb.x)};
    long long base = (long long)qrow * NC + chunk * 4;
    *(uint4*)(cand_p + base) = o;
  }
}

// ---------- Kernel 4: finalize: merge 784 -> top-16, fp64 rescore, top-8, usage, gather ----------
__global__ __launch_bounds__(256) void finalize_kernel(const unsigned int* __restrict__ cand_p,
                                                       const double* __restrict__ q64n,
                                                       const float* __restrict__ keys,
                                                       const double* __restrict__ kinv64,
                                                       const float* __restrict__ values,
                                                       float* __restrict__ scores_out,
                                                       float* __restrict__ out_rv,
                                                       float* __restrict__ usage_out) {
  const int q = blockIdx.x;
  const int tid = threadIdx.x;
  __shared__ int    cidx[NCAND];
  __shared__ double sc[NCAND];
  __shared__ double s8[8];
  __shared__ int    f8[8];

  // Phase A: wave 0 extracts bf16-top-16 of the 784 candidates
  if (tid < 64) {
    const int lane = tid;
    unsigned int lv[13];
    int li[13];
#pragma unroll
    for (int s = 0; s < 13; s++) {
      int c = lane + 64 * s;
      if (c < NC) {
        unsigned int p = cand_p[(long long)q * NC + c];
        lv[s] = p;
        li[s] = (c >> 2) * KCHUNK + (int)(p & 255u);
      } else { lv[s] = 0u; li[s] = 0x7fffffff; }
    }
#pragma unroll 1
    for (int r = 0; r < NCAND; r++) {
      unsigned int bv = 0u;
      int bi = 0x7fffffff;
#pragma unroll
      for (int s = 0; s < 13; s++)
        if (lv[s] > bv || (lv[s] == bv && li[s] < bi)) { bv = lv[s]; bi = li[s]; }
#pragma unroll
      for (int m = 32; m; m >>= 1) {
        unsigned int ov = (unsigned int)__shfl_xor((int)bv, m, 64);
        int oi = __shfl_xor(bi, m, 64);
        if (ov > bv || (ov == bv && oi < bi)) { bv = ov; bi = oi; }
      }
      if (lane == r) cidx[r] = bi;
#pragma unroll
      for (int s = 0; s < 13; s++)
        if (li[s] == bi) lv[s] = 0u;
    }
  }
  __syncthreads();

  // Phase B: fp64 rescore of 16 candidates (16 lanes each, 16 dims/lane)
  {
    const int g = tid >> 4, ll = tid & 15;
    int idx = cidx[g];
    double s = 0.0;
    const double* qrow = &q64n[(long long)q * D + ll * 16];
    const float* krow = &keys[(long long)idx * D + ll * 16];
#pragma unroll
    for (int t = 0; t < 16; t++) s = fma(qrow[t], (double)krow[t], s);
#pragma unroll
    for (int m = 8; m; m >>= 1) s += __shfl_xor(s, m, 16);
    if (ll == 0) sc[g] = s * kinv64[idx];
  }
  __syncthreads();

  // Phase C: serial exact top-8 of 16
  if (tid == 0) {
#pragma unroll 1
    for (int r = 0; r < 8; r++) {
      double bv = DNEG_INF;
      int bi = 0x7fffffff, bg = -1;
#pragma unroll
      for (int t = 0; t < NCAND; t++) {
        if (sc[t] > bv || (sc[t] == bv && cidx[t] < bi)) { bv = sc[t]; bi = cidx[t]; bg = t; }
      }
      s8[r] = bv; f8[r] = bi;
      sc[bg] = DNEG_INF;
    }
  }
  __syncthreads();
  if (tid < 8) {
    scores_out[q * 8 + tid] = (float)s8[tid];
    atomicAdd(&usage_out[f8[tid]], 1.0f);
  }

  // Phase D: gather 8 x 256 values
  {
    const int row = tid >> 5;
    const int c0 = (tid & 31) * 8;
    int idx = f8[row];
    float4 v0 = *(const float4*)(&values[(long long)idx * D + c0]);
    float4 v1 = *(const float4*)(&values[(long long)idx * D + c0 + 4]);
    long long obase = ((long long)q * 8 + row) * D + c0;
    *(float4*)(&out_rv[obase]) = v0;
    *(float4*)(&out_rv[obase + 4]) = v1;
  }
}

extern "C" void kernel_launch(void* const* d_in, const int* in_sizes, int n_in,
                              void* d_out, int out_size, void* d_ws, size_t ws_size,
                              hipStream_t stream) {
  (void)in_sizes; (void)n_in; (void)out_size; (void)ws_size;
  const float* query  = (const float*)d_in[0];
  const float* W      = (const float*)d_in[1];
  const float* b      = (const float*)d_in[2];
  const float* keys   = (const float*)d_in[3];
  const float* values = (const float*)d_in[4];
  const float* usage  = (const float*)d_in[5];

  float* out    = (float*)d_out;
  float* out_rv = out;                    // 2048*8*256
  float* out_sc = out + BQ * 8 * D;       // 2048*8
  float* out_us = out_sc + BQ * 8;        // 50000

  double*         q64n   = (double*)d_ws;                     // 524288 d  (4MB)
  double*         kinv64 = q64n + BQ * D;                     // 50000 d
  unsigned short* qbf    = (unsigned short*)(kinv64 + NKEYS); // 524288 us (1MB)
  unsigned short* kbf    = qbf + BQ * D;                      // 50176*256 (25.7MB)
  unsigned int*   cand_p = (unsigned int*)(kbf + (long long)NKPAD * D); // 2048*784 (6.4MB)

  hipLaunchKernelGGL(qnorm_kernel, dim3(BQ / 8), dim3(256), 0, stream, query, W, b, qbf, q64n);
  hipLaunchKernelGGL(kprep_kernel, dim3(NKPAD / 4), dim3(256), 0, stream, keys, usage, kinv64, kbf, out_us);
  // grid 3200 = 8 XCD-slots x 16 q-tiles x 25 chunk-groups (chunk >= 196 early-exits)
  hipLaunchKernelGGL(sim_mfma_kernel, dim3(3200), dim3(512), 0, stream, qbf, kbf, cand_p);
  hipLaunchKernelGGL(finalize_kernel, dim3(BQ), dim3(256), 0, stream, cand_p, q64n, keys, kinv64, values, out_sc, out_rv, out_us);
}

// Round 11
// 186.406 us; speedup vs baseline: 1.5348x; 1.5348x over previous
//
#include <hip/hip_runtime.h>

#define D 256
#define NKEYS 50000
#define KCHUNK 256
#define NCHUNK 196           // 50176 / 256
#define NKPAD (KCHUNK * NCHUNK)
#define BQ 2048
#define NC (NCHUNK * 4)      // 784 candidates/query
#define NCAND 16             // rescored candidates per query
#define DNEG_INF (-1.0e300)

typedef __attribute__((ext_vector_type(8))) __bf16 bf16x8;
typedef __attribute__((ext_vector_type(16))) float f32x16;

// round-to-nearest-even f32 -> bf16 bits
__device__ __forceinline__ unsigned short f2bf(float x) {
  unsigned int u = __float_as_uint(x);
  unsigned int r = (u + 0x7fffu + ((u >> 16) & 1u)) >> 16;
  return (unsigned short)r;
}

// ---------- Kernel 1: q = query @ W^T + b (fp64 accum), L2-normalize ----------
__global__ __launch_bounds__(256) void qnorm_kernel(const float* __restrict__ query,
                                                    const float* __restrict__ W,
                                                    const float* __restrict__ b,
                                                    unsigned short* __restrict__ qbf,
                                                    double* __restrict__ q64n) {
  __shared__ __align__(16) float As[8][20];
  __shared__ __align__(16) float Bs[256][20];
  const int tid = threadIdx.x;
  const int qt = tid >> 5;   // 0..7 -> row m0+qt
  const int nt = tid & 31;   // cols nt + 32*j, j<8
  const int m0 = blockIdx.x * 8;

  double acc[8];
#pragma unroll
  for (int j = 0; j < 8; j++) acc[j] = 0.0;

  for (int k0 = 0; k0 < D; k0 += 16) {
    if (tid < 32) {
      int r = tid >> 2, f = tid & 3;
      *(float4*)(&As[r][f * 4]) = *(const float4*)(&query[(m0 + r) * D + k0 + f * 4]);
    }
#pragma unroll
    for (int i = 0; i < 4; i++) {
      int r = (tid >> 2) + 64 * i, f = tid & 3;
      *(float4*)(&Bs[r][f * 4]) = *(const float4*)(&W[r * D + k0 + f * 4]);
    }
    __syncthreads();
#pragma unroll
    for (int kk = 0; kk < 16; kk += 4) {
      float4 af = *(const float4*)(&As[qt][kk]);
#pragma unroll
      for (int j = 0; j < 8; j++) {
        float4 bf = *(const float4*)(&Bs[nt + 32 * j][kk]);
        acc[j] = fma((double)af.x, (double)bf.x, acc[j]);
        acc[j] = fma((double)af.y, (double)bf.y, acc[j]);
        acc[j] = fma((double)af.z, (double)bf.z, acc[j]);
        acc[j] = fma((double)af.w, (double)bf.w, acc[j]);
      }
    }
    __syncthreads();
  }
#pragma unroll
  for (int j = 0; j < 8; j++) acc[j] += (double)b[nt + 32 * j];

  double s = 0.0;
#pragma unroll
  for (int j = 0; j < 8; j++) s = fma(acc[j], acc[j], s);
#pragma unroll
  for (int m = 16; m; m >>= 1) s += __shfl_xor(s, m, 32);
  double den = fmax(sqrt(s), 1e-12);
  int row = m0 + qt;
#pragma unroll
  for (int j = 0; j < 8; j++) {
    double v = acc[j] / den;
    q64n[row * D + nt + 32 * j] = v;
    qbf[row * D + nt + 32 * j] = f2bf((float)v);
  }
}

// ---------- Kernel 2: key prep (+ fused usage copy) ----------
// kbf row r = 512B (256 bf16 dims); elem e' = e ^ ((r&31)<<3)  (byte ^ ((r&31)<<4)).
__global__ __launch_bounds__(256) void kprep_kernel(const float* __restrict__ keys,
                                                    const float* __restrict__ usage,
                                                    double* __restrict__ kinv64,
                                                    unsigned short* __restrict__ kbf,
                                                    float* __restrict__ out_u) {
  int wave = threadIdx.x >> 6, lane = threadIdx.x & 63;
  int r = blockIdx.x * 4 + wave;
  if (r >= NKPAD) return;
  if (lane == 0 && r < NKEYS) out_u[r] = usage[r];
  int e = lane * 4;                    // 4 consecutive elems (low 3 bits intact)
  int e2 = e ^ ((r & 31) << 3);
  unsigned short* dst = kbf + (long long)r * D + e2;
  if (r >= NKEYS) {
    ushort4 z = {0, 0, 0, 0};
    *(ushort4*)dst = z;
    return;
  }
  float4 v = *(const float4*)(&keys[(long long)r * D + e]);
  double s = (double)v.x * v.x + (double)v.y * v.y + (double)v.z * v.z + (double)v.w * v.w;
#pragma unroll
  for (int m = 32; m; m >>= 1) s += __shfl_xor(s, m, 64);
  double inv = 1.0 / fmax(sqrt(s), 1e-12);
  if (lane == 0) kinv64[r] = inv;
  float fi = (float)inv;
  ushort4 o;
  o.x = f2bf(v.x * fi); o.y = f2bf(v.y * fi); o.z = f2bf(v.z * fi); o.w = f2bf(v.w * fi);
  *(ushort4*)dst = o;
}

// ---------- Kernel 3: 32x32x16 bf16 MFMA sim, 4 waves, 64q x 256k per block ----------
// Four key-stages of 64 full-dim keys (32KB LDS, 512B rows, conflict-free swizzle).
// Wave w: qg=w>>1 (32 queries), h=w&1 (32-key half of each 64-key stage).
// Round-8 XCD chunk-affinity grid (qt inner): FETCH stays ~17MB.
__global__ __launch_bounds__(256, 4) void sim_mfma_kernel(const unsigned short* __restrict__ qbf,
                                                          const unsigned short* __restrict__ kbf,
                                                          unsigned int* __restrict__ cand_p) {
  __shared__ __align__(16) unsigned char klds[64 * 512];    // 32KB
  __shared__ __align__(16) unsigned int mlds[2][32][2][4];  // 2KB pair-merge buffer
  const int bid = blockIdx.x;
  const int k8 = bid & 7;
  const int ii = bid >> 3;            // 0..799
  const int qt = ii & 31;             // 32 q-tiles of 64 (inner: consecutive blocks share chunk)
  const int chunk = (ii >> 5) * 8 + k8;
  if (chunk >= NCHUNK) return;
  const int n0 = chunk * KCHUNK;
  const int m0 = qt * 64;

  const int tid = threadIdx.x;
  const int w = tid >> 6;
  const int l = tid & 63;
  const int col = l & 31;
  const int hi = l >> 5;
  const int qg = w >> 1;
  const int h = w & 1;
  const int qrow = m0 + qg * 32 + col;

  // resident query B-fragments: kstep ks covers dims ks*16 + hi*8 .. +8
  bf16x8 qf[16];
#pragma unroll
  for (int ks = 0; ks < 16; ks++)
    qf[ks] = *(const bf16x8*)(qbf + (long long)qrow * D + ks * 16 + hi * 8);

  unsigned int s0 = 0u, s1 = 0u, s2 = 0u, s3 = 0u;
  const bool edge = (n0 + KCHUNK > NKEYS);
  const int rr = h * 32 + col;            // LDS row this lane reads
  const int rbase = rr * 512 + hi * 16;
  const int swz = col << 4;               // rr & 31 == col

#pragma unroll 1
  for (int st = 0; st < 4; st++) {
    __syncthreads();  // klds free
    // stage 32KB = rows n0 + st*64 .. +64 (linear copy; swizzle pre-baked in kbf)
#pragma unroll
    for (int i = 0; i < 8; i++) {
      int dstbase = i * 4096 + w * 1024;
      int off = dstbase + l * 16;
      int r_loc = off >> 9;
      const void* src = (const char*)kbf + ((long long)(n0 + st * 64 + r_loc) * 512 + (off & 511));
      __builtin_amdgcn_global_load_lds(src, (void*)(klds + dstbase), 16, 0, 0);
    }
    __syncthreads();  // drain

    f32x16 acc;
#pragma unroll
    for (int r = 0; r < 16; r++) acc[r] = 0.f;

#pragma unroll
    for (int ks = 0; ks < 16; ks++) {
      bf16x8 a = *(const bf16x8*)(klds + ((rbase + ks * 32) ^ swz));
      acc = __builtin_amdgcn_mfma_f32_32x32x16_bf16(a, qf[ks], acc, 0, 0, 0);
    }

    // pack + streaming insertion top-4 (slot = st*64 + h*32 + subrow, < 256)
#pragma unroll
    for (int r = 0; r < 16; r++) {
      unsigned int u = __float_as_uint(acc[r] + 2.0f);
      int slot = st * 64 + h * 32 + (r & 3) + 8 * (r >> 2) + 4 * hi;
      unsigned int v = (u & 0xFFFFFF00u) | (unsigned)slot;
      if (edge && (n0 + slot >= NKEYS)) v = 0u;
      unsigned int m0v = min(s0, v); s0 = max(s0, v);
      unsigned int m1v = min(s1, m0v); s1 = max(s1, m0v);
      unsigned int m2v = min(s2, m1v); s2 = max(s2, m1v);
      s3 = max(s3, m2v);
    }
  }

  // lane-pair merge (l ^ 32 = same query col, disjoint key subrows): bitonic + sort-4
  unsigned int b0 = (unsigned int)__shfl_xor((int)s0, 32, 64);
  unsigned int b1 = (unsigned int)__shfl_xor((int)s1, 32, 64);
  unsigned int b2 = (unsigned int)__shfl_xor((int)s2, 32, 64);
  unsigned int b3 = (unsigned int)__shfl_xor((int)s3, 32, 64);
  unsigned int t0 = max(s0, b3), t1 = max(s1, b2), t2 = max(s2, b1), t3 = max(s3, b0);
  unsigned int u0 = max(t0, t2), u2 = min(t0, t2), u1 = max(t1, t3), u3 = min(t1, t3);
  unsigned int w0 = max(u0, u1), w1 = min(u0, u1), w2 = max(u2, u3), w3 = min(u2, u3);

  // cross-wave (key-half h) merge via LDS; sorted inputs -> pairwise max
  if (hi == 0) {
    uint4 a = {w0, w1, w2, w3};
    *(uint4*)(&mlds[qg][col][h][0]) = a;
  }
  __syncthreads();
  if (h == 0 && hi == 0) {
    uint4 bb = *(const uint4*)(&mlds[qg][col][1][0]);
    uint4 o = {max(w0, bb.w), max(w1, bb.z), max(w2, bb.y), max(w3, bb.x)};
    long long base = (long long)qrow * NC + chunk * 4;
    *(uint4*)(cand_p + base) = o;
  }
}

// ---------- Kernel 4: finalize: merge 784 -> top-16, fp64 rescore, top-8, usage, gather ----------
__global__ __launch_bounds__(256) void finalize_kernel(const unsigned int* __restrict__ cand_p,
                                                       const double* __restrict__ q64n,
                                                       const float* __restrict__ keys,
                                                       const double* __restrict__ kinv64,
                                                       const float* __restrict__ values,
                                                       float* __restrict__ scores_out,
                                                       float* __restrict__ out_rv,
                                                       float* __restrict__ usage_out) {
  const int q = blockIdx.x;
  const int tid = threadIdx.x;
  __shared__ int    cidx[NCAND];
  __shared__ double sc[NCAND];
  __shared__ double s8[8];
  __shared__ int    f8[8];

  // Phase A: wave 0 extracts bf16-top-16 of the 784 candidates
  if (tid < 64) {
    const int lane = tid;
    unsigned int lv[13];
    int li[13];
#pragma unroll
    for (int s = 0; s < 13; s++) {
      int c = lane + 64 * s;
      if (c < NC) {
        unsigned int p = cand_p[(long long)q * NC + c];
        lv[s] = p;
        li[s] = (c >> 2) * KCHUNK + (int)(p & 255u);
      } else { lv[s] = 0u; li[s] = 0x7fffffff; }
    }
#pragma unroll 1
    for (int r = 0; r < NCAND; r++) {
      unsigned int bv = 0u;
      int bi = 0x7fffffff;
#pragma unroll
      for (int s = 0; s < 13; s++)
        if (lv[s] > bv || (lv[s] == bv && li[s] < bi)) { bv = lv[s]; bi = li[s]; }
#pragma unroll
      for (int m = 32; m; m >>= 1) {
        unsigned int ov = (unsigned int)__shfl_xor((int)bv, m, 64);
        int oi = __shfl_xor(bi, m, 64);
        if (ov > bv || (ov == bv && oi < bi)) { bv = ov; bi = oi; }
      }
      if (lane == r) cidx[r] = bi;
#pragma unroll
      for (int s = 0; s < 13; s++)
        if (li[s] == bi) lv[s] = 0u;
    }
  }
  __syncthreads();

  // Phase B: fp64 rescore of 16 candidates (16 lanes each, 16 dims/lane)
  {
    const int g = tid >> 4, ll = tid & 15;
    int idx = cidx[g];
    double s = 0.0;
    const double* qrow = &q64n[(long long)q * D + ll * 16];
    const float* krow = &keys[(long long)idx * D + ll * 16];
#pragma unroll
    for (int t = 0; t < 16; t++) s = fma(qrow[t], (double)krow[t], s);
#pragma unroll
    for (int m = 8; m; m >>= 1) s += __shfl_xor(s, m, 16);
    if (ll == 0) sc[g] = s * kinv64[idx];
  }
  __syncthreads();

  // Phase C: serial exact top-8 of 16
  if (tid == 0) {
#pragma unroll 1
    for (int r = 0; r < 8; r++) {
      double bv = DNEG_INF;
      int bi = 0x7fffffff, bg = -1;
#pragma unroll
      for (int t = 0; t < NCAND; t++) {
        if (sc[t] > bv || (sc[t] == bv && cidx[t] < bi)) { bv = sc[t]; bi = cidx[t]; bg = t; }
      }
      s8[r] = bv; f8[r] = bi;
      sc[bg] = DNEG_INF;
    }
  }
  __syncthreads();
  if (tid < 8) {
    scores_out[q * 8 + tid] = (float)s8[tid];
    atomicAdd(&usage_out[f8[tid]], 1.0f);
  }

  // Phase D: gather 8 x 256 values
  {
    const int row = tid >> 5;
    const int c0 = (tid & 31) * 8;
    int idx = f8[row];
    float4 v0 = *(const float4*)(&values[(long long)idx * D + c0]);
    float4 v1 = *(const float4*)(&values[(long long)idx * D + c0 + 4]);
    long long obase = ((long long)q * 8 + row) * D + c0;
    *(float4*)(&out_rv[obase]) = v0;
    *(float4*)(&out_rv[obase + 4]) = v1;
  }
}

extern "C" void kernel_launch(void* const* d_in, const int* in_sizes, int n_in,
                              void* d_out, int out_size, void* d_ws, size_t ws_size,
                              hipStream_t stream) {
  (void)in_sizes; (void)n_in; (void)out_size; (void)ws_size;
  const float* query  = (const float*)d_in[0];
  const float* W      = (const float*)d_in[1];
  const float* b      = (const float*)d_in[2];
  const float* keys   = (const float*)d_in[3];
  const float* values = (const float*)d_in[4];
  const float* usage  = (const float*)d_in[5];

  float* out    = (float*)d_out;
  float* out_rv = out;                    // 2048*8*256
  float* out_sc = out + BQ * 8 * D;       // 2048*8
  float* out_us = out_sc + BQ * 8;        // 50000

  double*         q64n   = (double*)d_ws;                     // 524288 d  (4MB)
  double*         kinv64 = q64n + BQ * D;                     // 50000 d
  unsigned short* qbf    = (unsigned short*)(kinv64 + NKEYS); // 524288 us (1MB)
  unsigned short* kbf    = qbf + BQ * D;                      // 50176*256 (25.7MB)
  unsigned int*   cand_p = (unsigned int*)(kbf + (long long)NKPAD * D); // 2048*784 (6.4MB)

  hipLaunchKernelGGL(qnorm_kernel, dim3(BQ / 8), dim3(256), 0, stream, query, W, b, qbf, q64n);
  hipLaunchKernelGGL(kprep_kernel, dim3(NKPAD / 4), dim3(256), 0, stream, keys, usage, kinv64, kbf, out_us);
  // grid 6400 = 8 XCD-slots x 32 q-tiles (inner) x 25 chunk-groups (chunk >= 196 early-exits)
  hipLaunchKernelGGL(sim_mfma_kernel, dim3(6400), dim3(256), 0, stream, qbf, kbf, cand_p);
  hipLaunchKernelGGL(finalize_kernel, dim3(BQ), dim3(256), 0, stream, cand_p, q64n, keys, kinv64, values, out_sc, out_rv, out_us);
}

// Round 12
// 163.094 us; speedup vs baseline: 1.7542x; 1.1429x over previous
//
#include <hip/hip_runtime.h>

#define D 256
#define NKEYS 50000
#define KCHUNK 256
#define NCHUNK 196           // 50176 / 256
#define NKPAD (KCHUNK * NCHUNK)
#define BQ 2048
#define NC (NCHUNK * 4)      // 784 candidates/query
#define NCAND 16             // rescored candidates per query
#define DNEG_INF (-1.0e300)

typedef __attribute__((ext_vector_type(8))) __bf16 bf16x8;
typedef __attribute__((ext_vector_type(16))) float f32x16;

// round-to-nearest-even f32 -> bf16 bits
__device__ __forceinline__ unsigned short f2bf(float x) {
  unsigned int u = __float_as_uint(x);
  unsigned int r = (u + 0x7fffu + ((u >> 16) & 1u)) >> 16;
  return (unsigned short)r;
}

// ---------- Kernel 1: fused prep ----------
// Blocks 0..255: qnorm (q = query@W^T+b fp64, L2-normalize -> qbf + q64n).
// Blocks 256.. : kprep (fp64 inv-norm, normalized bf16 keys pre-swizzled, usage copy).
// kbf row r = 512B; elem e' = e ^ ((r&31)<<3)  (byte ^ ((r&31)<<4)).
__global__ __launch_bounds__(256) void prep_kernel(const float* __restrict__ query,
                                                   const float* __restrict__ W,
                                                   const float* __restrict__ b,
                                                   const float* __restrict__ keys,
                                                   const float* __restrict__ usage,
                                                   unsigned short* __restrict__ qbf,
                                                   double* __restrict__ q64n,
                                                   double* __restrict__ kinv64,
                                                   unsigned short* __restrict__ kbf,
                                                   float* __restrict__ out_u) {
  __shared__ __align__(16) float As[8][20];
  __shared__ __align__(16) float Bs[256][20];
  if (blockIdx.x < 256) {
    const int tid = threadIdx.x;
    const int qt = tid >> 5;
    const int nt = tid & 31;
    const int m0 = blockIdx.x * 8;

    double acc[8];
#pragma unroll
    for (int j = 0; j < 8; j++) acc[j] = 0.0;

    for (int k0 = 0; k0 < D; k0 += 16) {
      if (tid < 32) {
        int r = tid >> 2, f = tid & 3;
        *(float4*)(&As[r][f * 4]) = *(const float4*)(&query[(m0 + r) * D + k0 + f * 4]);
      }
#pragma unroll
      for (int i = 0; i < 4; i++) {
        int r = (tid >> 2) + 64 * i, f = tid & 3;
        *(float4*)(&Bs[r][f * 4]) = *(const float4*)(&W[r * D + k0 + f * 4]);
      }
      __syncthreads();
#pragma unroll
      for (int kk = 0; kk < 16; kk += 4) {
        float4 af = *(const float4*)(&As[qt][kk]);
#pragma unroll
        for (int j = 0; j < 8; j++) {
          float4 bf = *(const float4*)(&Bs[nt + 32 * j][kk]);
          acc[j] = fma((double)af.x, (double)bf.x, acc[j]);
          acc[j] = fma((double)af.y, (double)bf.y, acc[j]);
          acc[j] = fma((double)af.z, (double)bf.z, acc[j]);
          acc[j] = fma((double)af.w, (double)bf.w, acc[j]);
        }
      }
      __syncthreads();
    }
#pragma unroll
    for (int j = 0; j < 8; j++) acc[j] += (double)b[nt + 32 * j];

    double s = 0.0;
#pragma unroll
    for (int j = 0; j < 8; j++) s = fma(acc[j], acc[j], s);
#pragma unroll
    for (int m = 16; m; m >>= 1) s += __shfl_xor(s, m, 32);
    double den = fmax(sqrt(s), 1e-12);
    int row = m0 + qt;
#pragma unroll
    for (int j = 0; j < 8; j++) {
      double v = acc[j] / den;
      q64n[row * D + nt + 32 * j] = v;
      qbf[row * D + nt + 32 * j] = f2bf((float)v);
    }
  } else {
    int wave = threadIdx.x >> 6, lane = threadIdx.x & 63;
    int r = (blockIdx.x - 256) * 4 + wave;
    if (r >= NKPAD) return;
    if (lane == 0 && r < NKEYS) out_u[r] = usage[r];
    int e = lane * 4;
    int e2 = e ^ ((r & 31) << 3);
    unsigned short* dst = kbf + (long long)r * D + e2;
    if (r >= NKEYS) {
      ushort4 z = {0, 0, 0, 0};
      *(ushort4*)dst = z;
      return;
    }
    float4 v = *(const float4*)(&keys[(long long)r * D + e]);
    double s = (double)v.x * v.x + (double)v.y * v.y + (double)v.z * v.z + (double)v.w * v.w;
#pragma unroll
    for (int m = 32; m; m >>= 1) s += __shfl_xor(s, m, 64);
    double inv = 1.0 / fmax(sqrt(s), 1e-12);
    if (lane == 0) kinv64[r] = inv;
    float fi = (float)inv;
    ushort4 o;
    o.x = f2bf(v.x * fi); o.y = f2bf(v.y * fi); o.z = f2bf(v.z * fi); o.w = f2bf(v.w * fi);
    *(ushort4*)dst = o;
  }
}

// ---------- Kernel 2: 32x32x16 bf16 MFMA sim, 4 waves, 128q x 256k per block ----------
// Eight 32-key stages, double-buffered 2x16KB LDS (512B conflict-free swizzled rows).
// Wave w owns 32 queries for the whole chunk (no cross-wave merge needed).
// Prefetch next stage before computing current; single barrier per stage (T3-lite).
__global__ __launch_bounds__(256, 4) void sim_mfma_kernel(const unsigned short* __restrict__ qbf,
                                                          const unsigned short* __restrict__ kbf,
                                                          unsigned int* __restrict__ cand_p) {
  __shared__ __align__(16) unsigned char klds[2][16384];   // 2 x 32 keys x 512B
  const int bid = blockIdx.x;
  const int k8 = bid & 7;
  const int ii = bid >> 3;            // 0..399
  const int qt = ii & 15;             // 16 q-tiles of 128 (inner: same chunk on one XCD)
  const int chunk = (ii >> 4) * 8 + k8;
  if (chunk >= NCHUNK) return;
  const int n0 = chunk * KCHUNK;
  const int m0 = qt * 128;

  const int tid = threadIdx.x;
  const int w = tid >> 6;             // wave = query group 0..3
  const int l = tid & 63;
  const int col = l & 31;
  const int hi = l >> 5;
  const int qrow = m0 + w * 32 + col;

  // resident query B-fragments: kstep ks covers dims ks*16 + hi*8 .. +8
  bf16x8 qf[16];
#pragma unroll
  for (int ks = 0; ks < 16; ks++)
    qf[ks] = *(const bf16x8*)(qbf + (long long)qrow * D + ks * 16 + hi * 8);

  unsigned int s0 = 0u, s1 = 0u, s2 = 0u, s3 = 0u;
  const bool edge = (n0 + KCHUNK > NKEYS);
  const int rbase = col * 512 + hi * 16;   // LDS row = col (32 rows/stage)
  const int swz = col << 4;
  const char* kchunk = (const char*)kbf + (long long)n0 * 512;

  auto prefetch = [&](unsigned char* buf, int kst) {
#pragma unroll
    for (int i = 0; i < 4; i++) {
      int dstbase = i * 4096 + w * 1024;        // wave-uniform LDS base
      int off = dstbase + l * 16;
      const void* src = kchunk + (long long)(kst * 32 + (off >> 9)) * 512 + (off & 511);
      __builtin_amdgcn_global_load_lds(src, (void*)(buf + dstbase), 16, 0, 0);
    }
  };

  auto compute = [&](const unsigned char* buf, int st) {
    f32x16 acc;
#pragma unroll
    for (int r = 0; r < 16; r++) acc[r] = 0.f;
#pragma unroll
    for (int ks = 0; ks < 16; ks++) {
      bf16x8 a = *(const bf16x8*)(buf + ((rbase + ks * 32) ^ swz));
      acc = __builtin_amdgcn_mfma_f32_32x32x16_bf16(a, qf[ks], acc, 0, 0, 0);
    }
    // pack (score+2.0 monotone u32, slot in low 8) + streaming insertion top-4
#pragma unroll
    for (int r = 0; r < 16; r++) {
      unsigned int u = __float_as_uint(acc[r] + 2.0f);
      int slot = st * 32 + (r & 3) + 8 * (r >> 2) + 4 * hi;
      unsigned int v = (u & 0xFFFFFF00u) | (unsigned)slot;
      if (edge && (n0 + slot >= NKEYS)) v = 0u;
      unsigned int a0 = min(s0, v); s0 = max(s0, v);
      unsigned int a1 = min(s1, a0); s1 = max(s1, a0);
      unsigned int a2 = min(s2, a1); s2 = max(s2, a1);
      s3 = max(s3, a2);
    }
  };

  prefetch(&klds[0][0], 0);
  __syncthreads();                    // drain stage 0

#pragma unroll 1
  for (int st = 0; st < 8; st += 2) {
    prefetch(&klds[1][0], st + 1);    // overlaps with compute below
    compute(&klds[0][0], st);
    __syncthreads();                  // drains prefetch vmcnt + readers of buf0
    if (st + 2 < 8) prefetch(&klds[0][0], st + 2);
    compute(&klds[1][0], st + 1);
    __syncthreads();
  }

  // lane-pair merge (l ^ 32 = same query col, disjoint key subrows): bitonic + sort-4
  unsigned int b0 = (unsigned int)__shfl_xor((int)s0, 32, 64);
  unsigned int b1 = (unsigned int)__shfl_xor((int)s1, 32, 64);
  unsigned int b2 = (unsigned int)__shfl_xor((int)s2, 32, 64);
  unsigned int b3 = (unsigned int)__shfl_xor((int)s3, 32, 64);
  unsigned int t0 = max(s0, b3), t1 = max(s1, b2), t2 = max(s2, b1), t3 = max(s3, b0);
  unsigned int u0 = max(t0, t2), u2 = min(t0, t2), u1 = max(t1, t3), u3 = min(t1, t3);
  unsigned int w0 = max(u0, u1), w1 = min(u0, u1), w2 = max(u2, u3), w3 = min(u2, u3);

  if (hi == 0) {
    uint4 o = {w0, w1, w2, w3};
    long long base = (long long)qrow * NC + chunk * 4;
    *(uint4*)(cand_p + base) = o;
  }
}

// ---------- Kernel 3: finalize: merge 784 -> top-16, fp64 rescore, top-8, usage, gather ----------
__global__ __launch_bounds__(256) void finalize_kernel(const unsigned int* __restrict__ cand_p,
                                                       const double* __restrict__ q64n,
                                                       const float* __restrict__ keys,
                                                       const double* __restrict__ kinv64,
                                                       const float* __restrict__ values,
                                                       float* __restrict__ scores_out,
                                                       float* __restrict__ out_rv,
                                                       float* __restrict__ usage_out) {
  const int q = blockIdx.x;
  const int tid = threadIdx.x;
  __shared__ int    cidx[NCAND];
  __shared__ double sc[NCAND];
  __shared__ double s8[8];
  __shared__ int    f8[8];

  // Phase A: wave 0 extracts bf16-top-16 of the 784 candidates
  if (tid < 64) {
    const int lane = tid;
    unsigned int lv[13];
    int li[13];
#pragma unroll
    for (int s = 0; s < 13; s++) {
      int c = lane + 64 * s;
      if (c < NC) {
        unsigned int p = cand_p[(long long)q * NC + c];
        lv[s] = p;
        li[s] = (c >> 2) * KCHUNK + (int)(p & 255u);
      } else { lv[s] = 0u; li[s] = 0x7fffffff; }
    }
#pragma unroll 1
    for (int r = 0; r < NCAND; r++) {
      unsigned int bv = 0u;
      int bi = 0x7fffffff;
#pragma unroll
      for (int s = 0; s < 13; s++)
        if (lv[s] > bv || (lv[s] == bv && li[s] < bi)) { bv = lv[s]; bi = li[s]; }
#pragma unroll
      for (int m = 32; m; m >>= 1) {
        unsigned int ov = (unsigned int)__shfl_xor((int)bv, m, 64);
        int oi = __shfl_xor(bi, m, 64);
        if (ov > bv || (ov == bv && oi < bi)) { bv = ov; bi = oi; }
      }
      if (lane == r) cidx[r] = bi;
#pragma unroll
      for (int s = 0; s < 13; s++)
        if (li[s] == bi) lv[s] = 0u;
    }
  }
  __syncthreads();

  // Phase B: fp64 rescore of 16 candidates (16 lanes each, 16 dims/lane)
  {
    const int g = tid >> 4, ll = tid & 15;
    int idx = cidx[g];
    double s = 0.0;
    const double* qrow = &q64n[(long long)q * D + ll * 16];
    const float* krow = &keys[(long long)idx * D + ll * 16];
#pragma unroll
    for (int t = 0; t < 16; t++) s = fma(qrow[t], (double)krow[t], s);
#pragma unroll
    for (int m = 8; m; m >>= 1) s += __shfl_xor(s, m, 16);
    if (ll == 0) sc[g] = s * kinv64[idx];
  }
  __syncthreads();

  // Phase C: serial exact top-8 of 16
  if (tid == 0) {
#pragma unroll 1
    for (int r = 0; r < 8; r++) {
      double bv = DNEG_INF;
      int bi = 0x7fffffff, bg = -1;
#pragma unroll
      for (int t = 0; t < NCAND; t++) {
        if (sc[t] > bv || (sc[t] == bv && cidx[t] < bi)) { bv = sc[t]; bi = cidx[t]; bg = t; }
      }
      s8[r] = bv; f8[r] = bi;
      sc[bg] = DNEG_INF;
    }
  }
  __syncthreads();
  if (tid < 8) {
    scores_out[q * 8 + tid] = (float)s8[tid];
    atomicAdd(&usage_out[f8[tid]], 1.0f);
  }

  // Phase D: gather 8 x 256 values
  {
    const int row = tid >> 5;
    const int c0 = (tid & 31) * 8;
    int idx = f8[row];
    float4 v0 = *(const float4*)(&values[(long long)idx * D + c0]);
    float4 v1 = *(const float4*)(&values[(long long)idx * D + c0 + 4]);
    long long obase = ((long long)q * 8 + row) * D + c0;
    *(float4*)(&out_rv[obase]) = v0;
    *(float4*)(&out_rv[obase + 4]) = v1;
  }
}

extern "C" void kernel_launch(void* const* d_in, const int* in_sizes, int n_in,
                              void* d_out, int out_size, void* d_ws, size_t ws_size,
                              hipStream_t stream) {
  (void)in_sizes; (void)n_in; (void)out_size; (void)ws_size;
  const float* query  = (const float*)d_in[0];
  const float* W      = (const float*)d_in[1];
  const float* b      = (const float*)d_in[2];
  const float* keys   = (const float*)d_in[3];
  const float* values = (const float*)d_in[4];
  const float* usage  = (const float*)d_in[5];

  float* out    = (float*)d_out;
  float* out_rv = out;                    // 2048*8*256
  float* out_sc = out + BQ * 8 * D;       // 2048*8
  float* out_us = out_sc + BQ * 8;        // 50000

  double*         q64n   = (double*)d_ws;                     // 524288 d  (4MB)
  double*         kinv64 = q64n + BQ * D;                     // 50000 d
  unsigned short* qbf    = (unsigned short*)(kinv64 + NKEYS); // 524288 us (1MB)
  unsigned short* kbf    = qbf + BQ * D;                      // 50176*256 (25.7MB)
  unsigned int*   cand_p = (unsigned int*)(kbf + (long long)NKPAD * D); // 2048*784 (6.4MB)

  // prep: 256 qnorm blocks + 12544 kprep blocks in one launch (parallel execution)
  hipLaunchKernelGGL(prep_kernel, dim3(256 + NKPAD / 4), dim3(256), 0, stream,
                     query, W, b, keys, usage, qbf, q64n, kinv64, kbf, out_us);
  // grid 3200 = 8 XCD-slots x 16 q-tiles (inner) x 25 chunk-groups (chunk >= 196 early-exits)
  hipLaunchKernelGGL(sim_mfma_kernel, dim3(3200), dim3(256), 0, stream, qbf, kbf, cand_p);
  hipLaunchKernelGGL(finalize_kernel, dim3(BQ), dim3(256), 0, stream, cand_p, q64n, keys, kinv64, values, out_sc, out_rv, out_us);
}

// Round 13
// 159.603 us; speedup vs baseline: 1.7925x; 1.0219x over previous
//
#include <hip/hip_runtime.h>

#define D 256
#define NKEYS 50000
#define KCHUNK 256
#define NCHUNK 196           // 50176 / 256
#define NKPAD (KCHUNK * NCHUNK)
#define BQ 2048
#define NC (NCHUNK * 4)      // 784 candidates/query
#define NCAND 24             // rescored candidates per query (12 per half-wave)
#define DNEG_INF (-1.0e300)

typedef __attribute__((ext_vector_type(8))) __bf16 bf16x8;
typedef __attribute__((ext_vector_type(16))) float f32x16;

// round-to-nearest-even f32 -> bf16 bits
__device__ __forceinline__ unsigned short f2bf(float x) {
  unsigned int u = __float_as_uint(x);
  unsigned int r = (u + 0x7fffu + ((u >> 16) & 1u)) >> 16;
  return (unsigned short)r;
}

// v_med3_u32: median of 3 unsigned (single VOP3 instruction on gfx950)
__device__ __forceinline__ unsigned int med3u(unsigned int a, unsigned int b, unsigned int c) {
  unsigned int d;
  asm("v_med3_u32 %0, %1, %2, %3" : "=v"(d) : "v"(a), "v"(b), "v"(c));
  return d;
}

// ---------- Kernel 1: fused prep ----------
// Blocks 0..255: qnorm (q = query@W^T+b fp64, L2-normalize -> qbf + q64n).
// Blocks 256.. : kprep (fp64 inv-norm, normalized bf16 keys pre-swizzled, usage copy).
// kbf row r = 512B; elem e' = e ^ ((r&31)<<3)  (byte ^ ((r&31)<<4)).
__global__ __launch_bounds__(256) void prep_kernel(const float* __restrict__ query,
                                                   const float* __restrict__ W,
                                                   const float* __restrict__ b,
                                                   const float* __restrict__ keys,
                                                   const float* __restrict__ usage,
                                                   unsigned short* __restrict__ qbf,
                                                   double* __restrict__ q64n,
                                                   double* __restrict__ kinv64,
                                                   unsigned short* __restrict__ kbf,
                                                   float* __restrict__ out_u) {
  __shared__ __align__(16) float As[8][20];
  __shared__ __align__(16) float Bs[256][20];
  if (blockIdx.x < 256) {
    const int tid = threadIdx.x;
    const int qt = tid >> 5;
    const int nt = tid & 31;
    const int m0 = blockIdx.x * 8;

    double acc[8];
#pragma unroll
    for (int j = 0; j < 8; j++) acc[j] = 0.0;

    for (int k0 = 0; k0 < D; k0 += 16) {
      if (tid < 32) {
        int r = tid >> 2, f = tid & 3;
        *(float4*)(&As[r][f * 4]) = *(const float4*)(&query[(m0 + r) * D + k0 + f * 4]);
      }
#pragma unroll
      for (int i = 0; i < 4; i++) {
        int r = (tid >> 2) + 64 * i, f = tid & 3;
        *(float4*)(&Bs[r][f * 4]) = *(const float4*)(&W[r * D + k0 + f * 4]);
      }
      __syncthreads();
#pragma unroll
      for (int kk = 0; kk < 16; kk += 4) {
        float4 af = *(const float4*)(&As[qt][kk]);
#pragma unroll
        for (int j = 0; j < 8; j++) {
          float4 bf = *(const float4*)(&Bs[nt + 32 * j][kk]);
          acc[j] = fma((double)af.x, (double)bf.x, acc[j]);
          acc[j] = fma((double)af.y, (double)bf.y, acc[j]);
          acc[j] = fma((double)af.z, (double)bf.z, acc[j]);
          acc[j] = fma((double)af.w, (double)bf.w, acc[j]);
        }
      }
      __syncthreads();
    }
#pragma unroll
    for (int j = 0; j < 8; j++) acc[j] += (double)b[nt + 32 * j];

    double s = 0.0;
#pragma unroll
    for (int j = 0; j < 8; j++) s = fma(acc[j], acc[j], s);
#pragma unroll
    for (int m = 16; m; m >>= 1) s += __shfl_xor(s, m, 32);
    double den = fmax(sqrt(s), 1e-12);
    int row = m0 + qt;
#pragma unroll
    for (int j = 0; j < 8; j++) {
      double v = acc[j] / den;
      q64n[row * D + nt + 32 * j] = v;
      qbf[row * D + nt + 32 * j] = f2bf((float)v);
    }
  } else {
    int wave = threadIdx.x >> 6, lane = threadIdx.x & 63;
    int r = (blockIdx.x - 256) * 4 + wave;
    if (r >= NKPAD) return;
    if (lane == 0 && r < NKEYS) out_u[r] = usage[r];
    int e = lane * 4;
    int e2 = e ^ ((r & 31) << 3);
    unsigned short* dst = kbf + (long long)r * D + e2;
    if (r >= NKEYS) {
      ushort4 z = {0, 0, 0, 0};
      *(ushort4*)dst = z;
      return;
    }
    float4 v = *(const float4*)(&keys[(long long)r * D + e]);
    double s = (double)v.x * v.x + (double)v.y * v.y + (double)v.z * v.z + (double)v.w * v.w;
#pragma unroll
    for (int m = 32; m; m >>= 1) s += __shfl_xor(s, m, 64);
    double inv = 1.0 / fmax(sqrt(s), 1e-12);
    if (lane == 0) kinv64[r] = inv;
    float fi = (float)inv;
    ushort4 o;
    o.x = f2bf(v.x * fi); o.y = f2bf(v.y * fi); o.z = f2bf(v.z * fi); o.w = f2bf(v.w * fi);
    *(ushort4*)dst = o;
  }
}

// ---------- Kernel 2: 32x32x16 bf16 MFMA sim, 4 waves, 128q x 256k per block ----------
// Eight 32-key stages, double-buffered 2x16KB LDS (512B conflict-free swizzled rows).
// Wave w owns 32 queries for the whole chunk. Prefetch-next-then-compute pipeline.
// Selection: pack (score+2.0 monotone u32 | slot) + med3-based sorted-top-4 insert (4 ops).
__global__ __launch_bounds__(256, 4) void sim_mfma_kernel(const unsigned short* __restrict__ qbf,
                                                          const unsigned short* __restrict__ kbf,
                                                          unsigned int* __restrict__ cand_p) {
  __shared__ __align__(16) unsigned char klds[2][16384];   // 2 x 32 keys x 512B
  const int bid = blockIdx.x;
  const int k8 = bid & 7;
  const int ii = bid >> 3;            // 0..399
  const int qt = ii & 15;             // 16 q-tiles of 128 (inner: same chunk on one XCD)
  const int chunk = (ii >> 4) * 8 + k8;
  if (chunk >= NCHUNK) return;
  const int n0 = chunk * KCHUNK;
  const int m0 = qt * 128;

  const int tid = threadIdx.x;
  const int w = tid >> 6;             // wave = query group 0..3
  const int l = tid & 63;
  const int col = l & 31;
  const int hi = l >> 5;
  const int qrow = m0 + w * 32 + col;

  // resident query B-fragments: kstep ks covers dims ks*16 + hi*8 .. +8
  bf16x8 qf[16];
#pragma unroll
  for (int ks = 0; ks < 16; ks++)
    qf[ks] = *(const bf16x8*)(qbf + (long long)qrow * D + ks * 16 + hi * 8);

  unsigned int s0 = 0u, s1 = 0u, s2 = 0u, s3 = 0u;
  const bool edge = (n0 + KCHUNK > NKEYS);
  const int rbase = col * 512 + hi * 16;   // LDS row = col (32 rows/stage)
  const int swz = col << 4;
  const char* kchunk = (const char*)kbf + (long long)n0 * 512;

  auto prefetch = [&](unsigned char* buf, int kst) {
#pragma unroll
    for (int i = 0; i < 4; i++) {
      int dstbase = i * 4096 + w * 1024;        // wave-uniform LDS base
      int off = dstbase + l * 16;
      const void* src = kchunk + (long long)(kst * 32 + (off >> 9)) * 512 + (off & 511);
      __builtin_amdgcn_global_load_lds(src, (void*)(buf + dstbase), 16, 0, 0);
    }
  };

  auto compute = [&](const unsigned char* buf, int st) {
    f32x16 acc;
#pragma unroll
    for (int r = 0; r < 16; r++) acc[r] = 0.f;
#pragma unroll
    for (int ks = 0; ks < 16; ks++) {
      bf16x8 a = *(const bf16x8*)(buf + ((rbase + ks * 32) ^ swz));
      acc = __builtin_amdgcn_mfma_f32_32x32x16_bf16(a, qf[ks], acc, 0, 0, 0);
    }
    // pack + med3 sorted-top-4 insert (all med3 read OLD state: depth-1 chain)
#pragma unroll
    for (int r = 0; r < 16; r++) {
      unsigned int u = __float_as_uint(acc[r] + 2.0f);
      int slot = st * 32 + (r & 3) + 8 * (r >> 2) + 4 * hi;
      unsigned int v = (u & 0xFFFFFF00u) | (unsigned)slot;
      if (edge && (n0 + slot >= NKEYS)) v = 0u;
      unsigned int n1 = med3u(s0, s1, v);
      unsigned int n2 = med3u(s1, s2, v);
      unsigned int n3 = med3u(s2, s3, v);
      s0 = max(s0, v);
      s1 = n1; s2 = n2; s3 = n3;
    }
  };

  prefetch(&klds[0][0], 0);
  __syncthreads();                    // drain stage 0

#pragma unroll 1
  for (int st = 0; st < 8; st += 2) {
    prefetch(&klds[1][0], st + 1);    // overlaps with compute below
    compute(&klds[0][0], st);
    __syncthreads();                  // drains prefetch vmcnt + readers of buf0
    if (st + 2 < 8) prefetch(&klds[0][0], st + 2);
    compute(&klds[1][0], st + 1);
    __syncthreads();
  }

  // lane-pair merge (l ^ 32 = same query col, disjoint key subrows): bitonic + sort-4
  unsigned int b0 = (unsigned int)__shfl_xor((int)s0, 32, 64);
  unsigned int b1 = (unsigned int)__shfl_xor((int)s1, 32, 64);
  unsigned int b2 = (unsigned int)__shfl_xor((int)s2, 32, 64);
  unsigned int b3 = (unsigned int)__shfl_xor((int)s3, 32, 64);
  unsigned int t0 = max(s0, b3), t1 = max(s1, b2), t2 = max(s2, b1), t3 = max(s3, b0);
  unsigned int u0 = max(t0, t2), u2 = min(t0, t2), u1 = max(t1, t3), u3 = min(t1, t3);
  unsigned int w0 = max(u0, u1), w1 = min(u0, u1), w2 = max(u2, u3), w3 = min(u2, u3);

  if (hi == 0) {
    uint4 o = {w0, w1, w2, w3};
    long long base = (long long)qrow * NC + chunk * 4;
    *(uint4*)(cand_p + base) = o;
  }
}

// ---------- Kernel 3: finalize: 2-wave merge 784 -> top-24, fp64 rescore, top-8, usage, gather ----------
__global__ __launch_bounds__(256) void finalize_kernel(const unsigned int* __restrict__ cand_p,
                                                       const double* __restrict__ q64n,
                                                       const float* __restrict__ keys,
                                                       const double* __restrict__ kinv64,
                                                       const float* __restrict__ values,
                                                       float* __restrict__ scores_out,
                                                       float* __restrict__ out_rv,
                                                       float* __restrict__ usage_out) {
  const int q = blockIdx.x;
  const int tid = threadIdx.x;
  __shared__ int    cidx[NCAND];
  __shared__ double sc[NCAND];
  __shared__ double s8[8];
  __shared__ int    f8[8];

  // Phase A: waves 0,1 each extract bf16-top-12 of their 392-candidate half.
  // (an item with global bf16-rank <= 12 has <= 11 superiors -> half-rank <= 12,
  //  so the union of half-top-12s provably contains the global bf16-top-12.)
  if (tid < 128) {
    const int half = tid >> 6;       // 0 or 1
    const int lane = tid & 63;
    const int base = half * 392;
    unsigned int lv[7];
    int li[7];
#pragma unroll
    for (int s = 0; s < 7; s++) {
      int c = lane + 64 * s;
      if (c < 392) {
        int cg = base + c;
        unsigned int p = cand_p[(long long)q * NC + cg];
        lv[s] = p;
        li[s] = (cg >> 2) * KCHUNK + (int)(p & 255u);
      } else { lv[s] = 0u; li[s] = 0x7fffffff; }
    }
#pragma unroll 1
    for (int r = 0; r < 12; r++) {
      unsigned int bv = 0u;
      int bi = 0x7fffffff;
#pragma unroll
      for (int s = 0; s < 7; s++)
        if (lv[s] > bv || (lv[s] == bv && li[s] < bi)) { bv = lv[s]; bi = li[s]; }
#pragma unroll
      for (int m = 32; m; m >>= 1) {
        unsigned int ov = (unsigned int)__shfl_xor((int)bv, m, 64);
        int oi = __shfl_xor(bi, m, 64);
        if (ov > bv || (ov == bv && oi < bi)) { bv = ov; bi = oi; }
      }
      if (lane == r) cidx[half * 12 + r] = bi;
#pragma unroll
      for (int s = 0; s < 7; s++)
        if (li[s] == bi) lv[s] = 0u;
    }
  }
  __syncthreads();

  // Phase B: fp64 rescore of 24 candidates (8 lanes each, 32 dims/lane)
  {
    const int g = tid >> 3, ll = tid & 7;
    if (g < NCAND) {
      int idx = cidx[g];
      double s = 0.0;
      const double* qrow = &q64n[(long long)q * D + ll * 32];
      const float* krow = &keys[(long long)idx * D + ll * 32];
#pragma unroll
      for (int t = 0; t < 32; t++) s = fma(qrow[t], (double)krow[t], s);
#pragma unroll
      for (int m = 4; m; m >>= 1) s += __shfl_xor(s, m, 8);
      if (ll == 0) sc[g] = s * kinv64[idx];
    }
  }
  __syncthreads();

  // Phase C: serial exact top-8 of 24 (duplicates across halves impossible: disjoint ranges)
  if (tid == 0) {
#pragma unroll 1
    for (int r = 0; r < 8; r++) {
      double bv = DNEG_INF;
      int bi = 0x7fffffff, bg = -1;
#pragma unroll
      for (int t = 0; t < NCAND; t++) {
        if (sc[t] > bv || (sc[t] == bv && cidx[t] < bi)) { bv = sc[t]; bi = cidx[t]; bg = t; }
      }
      s8[r] = bv; f8[r] = bi;
      sc[bg] = DNEG_INF;
    }
  }
  __syncthreads();
  if (tid < 8) {
    scores_out[q * 8 + tid] = (float)s8[tid];
    atomicAdd(&usage_out[f8[tid]], 1.0f);
  }

  // Phase D: gather 8 x 256 values
  {
    const int row = tid >> 5;
    const int c0 = (tid & 31) * 8;
    int idx = f8[row];
    float4 v0 = *(const float4*)(&values[(long long)idx * D + c0]);
    float4 v1 = *(const float4*)(&values[(long long)idx * D + c0 + 4]);
    long long obase = ((long long)q * 8 + row) * D + c0;
    *(float4*)(&out_rv[obase]) = v0;
    *(float4*)(&out_rv[obase + 4]) = v1;
  }
}

extern "C" void kernel_launch(void* const* d_in, const int* in_sizes, int n_in,
                              void* d_out, int out_size, void* d_ws, size_t ws_size,
                              hipStream_t stream) {
  (void)in_sizes; (void)n_in; (void)out_size; (void)ws_size;
  const float* query  = (const float*)d_in[0];
  const float* W      = (const float*)d_in[1];
  const float* b      = (const float*)d_in[2];
  const float* keys   = (const float*)d_in[3];
  const float* values = (const float*)d_in[4];
  const float* usage  = (const float*)d_in[5];

  float* out    = (float*)d_out;
  float* out_rv = out;                    // 2048*8*256
  float* out_sc = out + BQ * 8 * D;       // 2048*8
  float* out_us = out_sc + BQ * 8;        // 50000

  double*         q64n   = (double*)d_ws;                     // 524288 d  (4MB)
  double*         kinv64 = q64n + BQ * D;                     // 50000 d
  unsigned short* qbf    = (unsigned short*)(kinv64 + NKEYS); // 524288 us (1MB)
  unsigned short* kbf    = qbf + BQ * D;                      // 50176*256 (25.7MB)
  unsigned int*   cand_p = (unsigned int*)(kbf + (long long)NKPAD * D); // 2048*784 (6.4MB)

  // prep: 256 qnorm blocks + 12544 kprep blocks in one launch (parallel execution)
  hipLaunchKernelGGL(prep_kernel, dim3(256 + NKPAD / 4), dim3(256), 0, stream,
                     query, W, b, keys, usage, qbf, q64n, kinv64, kbf, out_us);
  // grid 3200 = 8 XCD-slots x 16 q-tiles (inner) x 25 chunk-groups (chunk >= 196 early-exits)
  hipLaunchKernelGGL(sim_mfma_kernel, dim3(3200), dim3(256), 0, stream, qbf, kbf, cand_p);
  hipLaunchKernelGGL(finalize_kernel, dim3(BQ), dim3(256), 0, stream, cand_p, q64n, keys, kinv64, values, out_sc, out_rv, out_us);
}

// Round 14
// 130.893 us; speedup vs baseline: 2.1857x; 1.2193x over previous
//
#include <hip/hip_runtime.h>

#define D 256
#define NKEYS 50000
#define KCHUNK 256
#define NCHUNK 196           // 50176 / 256
#define NKPAD (KCHUNK * NCHUNK)
#define BQ 2048
#define NC (NCHUNK * 4)      // 784 candidates/query
#define NCAND 16             // rescored candidates per query
#define DNEG_INF (-1.0e300)

typedef __attribute__((ext_vector_type(8))) __bf16 bf16x8;
typedef __attribute__((ext_vector_type(16))) float f32x16;

// round-to-nearest-even f32 -> bf16 bits
__device__ __forceinline__ unsigned short f2bf(float x) {
  unsigned int u = __float_as_uint(x);
  unsigned int r = (u + 0x7fffu + ((u >> 16) & 1u)) >> 16;
  return (unsigned short)r;
}

// v_med3_u32: median of 3 unsigned (single VOP3 instruction on gfx950)
__device__ __forceinline__ unsigned int med3u(unsigned int a, unsigned int b, unsigned int c) {
  unsigned int d;
  asm("v_med3_u32 %0, %1, %2, %3" : "=v"(d) : "v"(a), "v"(b), "v"(c));
  return d;
}

// ---------- Kernel 1: fused prep ----------
// Blocks 0..255: qnorm (q = query@W^T+b fp64, L2-normalize -> qbf + q64n).
// Blocks 256.. : kprep (fp64 inv-norm, normalized bf16 keys pre-swizzled, usage copy).
// kbf row r = 512B; elem e' = e ^ ((r&31)<<3)  (byte ^ ((r&31)<<4)).
__global__ __launch_bounds__(256) void prep_kernel(const float* __restrict__ query,
                                                   const float* __restrict__ W,
                                                   const float* __restrict__ b,
                                                   const float* __restrict__ keys,
                                                   const float* __restrict__ usage,
                                                   unsigned short* __restrict__ qbf,
                                                   double* __restrict__ q64n,
                                                   double* __restrict__ kinv64,
                                                   unsigned short* __restrict__ kbf,
                                                   float* __restrict__ out_u) {
  __shared__ __align__(16) float As[8][20];
  __shared__ __align__(16) float Bs[256][20];
  if (blockIdx.x < 256) {
    const int tid = threadIdx.x;
    const int qt = tid >> 5;
    const int nt = tid & 31;
    const int m0 = blockIdx.x * 8;

    double acc[8];
#pragma unroll
    for (int j = 0; j < 8; j++) acc[j] = 0.0;

    for (int k0 = 0; k0 < D; k0 += 16) {
      if (tid < 32) {
        int r = tid >> 2, f = tid & 3;
        *(float4*)(&As[r][f * 4]) = *(const float4*)(&query[(m0 + r) * D + k0 + f * 4]);
      }
#pragma unroll
      for (int i = 0; i < 4; i++) {
        int r = (tid >> 2) + 64 * i, f = tid & 3;
        *(float4*)(&Bs[r][f * 4]) = *(const float4*)(&W[r * D + k0 + f * 4]);
      }
      __syncthreads();
#pragma unroll
      for (int kk = 0; kk < 16; kk += 4) {
        float4 af = *(const float4*)(&As[qt][kk]);
#pragma unroll
        for (int j = 0; j < 8; j++) {
          float4 bf = *(const float4*)(&Bs[nt + 32 * j][kk]);
          acc[j] = fma((double)af.x, (double)bf.x, acc[j]);
          acc[j] = fma((double)af.y, (double)bf.y, acc[j]);
          acc[j] = fma((double)af.z, (double)bf.z, acc[j]);
          acc[j] = fma((double)af.w, (double)bf.w, acc[j]);
        }
      }
      __syncthreads();
    }
#pragma unroll
    for (int j = 0; j < 8; j++) acc[j] += (double)b[nt + 32 * j];

    double s = 0.0;
#pragma unroll
    for (int j = 0; j < 8; j++) s = fma(acc[j], acc[j], s);
#pragma unroll
    for (int m = 16; m; m >>= 1) s += __shfl_xor(s, m, 32);
    double den = fmax(sqrt(s), 1e-12);
    int row = m0 + qt;
#pragma unroll
    for (int j = 0; j < 8; j++) {
      double v = acc[j] / den;
      q64n[row * D + nt + 32 * j] = v;
      qbf[row * D + nt + 32 * j] = f2bf((float)v);
    }
  } else {
    int wave = threadIdx.x >> 6, lane = threadIdx.x & 63;
    int r = (blockIdx.x - 256) * 4 + wave;
    if (r >= NKPAD) return;
    if (lane == 0 && r < NKEYS) out_u[r] = usage[r];
    int e = lane * 4;
    int e2 = e ^ ((r & 31) << 3);
    unsigned short* dst = kbf + (long long)r * D + e2;
    if (r >= NKEYS) {
      ushort4 z = {0, 0, 0, 0};
      *(ushort4*)dst = z;
      return;
    }
    float4 v = *(const float4*)(&keys[(long long)r * D + e]);
    double s = (double)v.x * v.x + (double)v.y * v.y + (double)v.z * v.z + (double)v.w * v.w;
#pragma unroll
    for (int m = 32; m; m >>= 1) s += __shfl_xor(s, m, 64);
    double inv = 1.0 / fmax(sqrt(s), 1e-12);
    if (lane == 0) kinv64[r] = inv;
    float fi = (float)inv;
    ushort4 o;
    o.x = f2bf(v.x * fi); o.y = f2bf(v.y * fi); o.z = f2bf(v.z * fi); o.w = f2bf(v.w * fi);
    *(ushort4*)dst = o;
  }
}

// ---------- Kernel 2: 32x32x16 bf16 MFMA sim, 4 waves, 128q x 256k per block ----------
// Eight 32-key stages, double-buffered 2x16KB LDS (512B conflict-free swizzled rows).
// Wave w owns 32 queries. Prefetch-next-then-compute pipeline.
// acc init = 2.0f carries the pack bias through MFMA (pack = 1 v_and_or + med3 insert).
__global__ __launch_bounds__(256, 4) void sim_mfma_kernel(const unsigned short* __restrict__ qbf,
                                                          const unsigned short* __restrict__ kbf,
                                                          unsigned int* __restrict__ cand_p) {
  __shared__ __align__(16) unsigned char klds[2][16384];   // 2 x 32 keys x 512B
  const int bid = blockIdx.x;
  const int k8 = bid & 7;
  const int ii = bid >> 3;            // 0..399
  const int qt = ii & 15;             // 16 q-tiles of 128 (inner: same chunk on one XCD)
  const int chunk = (ii >> 4) * 8 + k8;
  if (chunk >= NCHUNK) return;
  const int n0 = chunk * KCHUNK;
  const int m0 = qt * 128;

  const int tid = threadIdx.x;
  const int w = tid >> 6;             // wave = query group 0..3
  const int l = tid & 63;
  const int col = l & 31;
  const int hi = l >> 5;
  const int qrow = m0 + w * 32 + col;

  // resident query B-fragments: kstep ks covers dims ks*16 + hi*8 .. +8
  bf16x8 qf[16];
#pragma unroll
  for (int ks = 0; ks < 16; ks++)
    qf[ks] = *(const bf16x8*)(qbf + (long long)qrow * D + ks * 16 + hi * 8);

  unsigned int s0 = 0u, s1 = 0u, s2 = 0u, s3 = 0u;
  const bool edge = (n0 + KCHUNK > NKEYS);
  const int rbase = col * 512 + hi * 16;   // LDS row = col (32 rows/stage)
  const int swz = col << 4;
  const char* kchunk = (const char*)kbf + (long long)n0 * 512;

  auto prefetch = [&](unsigned char* buf, int kst) {
#pragma unroll
    for (int i = 0; i < 4; i++) {
      int dstbase = i * 4096 + w * 1024;        // wave-uniform LDS base
      int off = dstbase + l * 16;
      const void* src = kchunk + (long long)(kst * 32 + (off >> 9)) * 512 + (off & 511);
      __builtin_amdgcn_global_load_lds(src, (void*)(buf + dstbase), 16, 0, 0);
    }
  };

  auto compute = [&](const unsigned char* buf, int st) {
    f32x16 acc;
#pragma unroll
    for (int r = 0; r < 16; r++) acc[r] = 2.0f;   // pack bias rides in the accumulator
#pragma unroll
    for (int ks = 0; ks < 16; ks++) {
      bf16x8 a = *(const bf16x8*)(buf + ((rbase + ks * 32) ^ swz));
      acc = __builtin_amdgcn_mfma_f32_32x32x16_bf16(a, qf[ks], acc, 0, 0, 0);
    }
    // pack (monotone u32 | slot) + med3 sorted-top-4 insert (depth-1 chain)
#pragma unroll
    for (int r = 0; r < 16; r++) {
      unsigned int u = __float_as_uint(acc[r]);
      int slot = st * 32 + (r & 3) + 8 * (r >> 2) + 4 * hi;
      unsigned int v = (u & 0xFFFFFF00u) | (unsigned)slot;
      if (edge && (n0 + slot >= NKEYS)) v = 0u;
      unsigned int n1 = med3u(s0, s1, v);
      unsigned int n2 = med3u(s1, s2, v);
      unsigned int n3 = med3u(s2, s3, v);
      s0 = max(s0, v);
      s1 = n1; s2 = n2; s3 = n3;
    }
  };

  prefetch(&klds[0][0], 0);
  __syncthreads();                    // drain stage 0

#pragma unroll 1
  for (int st = 0; st < 8; st += 2) {
    prefetch(&klds[1][0], st + 1);    // overlaps with compute below
    compute(&klds[0][0], st);
    __syncthreads();                  // drains prefetch vmcnt + readers of buf0
    if (st + 2 < 8) prefetch(&klds[0][0], st + 2);
    compute(&klds[1][0], st + 1);
    __syncthreads();
  }

  // lane-pair merge (l ^ 32 = same query col, disjoint key subrows): bitonic + sort-4
  unsigned int b0 = (unsigned int)__shfl_xor((int)s0, 32, 64);
  unsigned int b1 = (unsigned int)__shfl_xor((int)s1, 32, 64);
  unsigned int b2 = (unsigned int)__shfl_xor((int)s2, 32, 64);
  unsigned int b3 = (unsigned int)__shfl_xor((int)s3, 32, 64);
  unsigned int t0 = max(s0, b3), t1 = max(s1, b2), t2 = max(s2, b1), t3 = max(s3, b0);
  unsigned int u0 = max(t0, t2), u2 = min(t0, t2), u1 = max(t1, t3), u3 = min(t1, t3);
  unsigned int w0 = max(u0, u1), w1 = min(u0, u1), w2 = max(u2, u3), w3 = min(u2, u3);

  if (hi == 0) {
    uint4 o = {w0, w1, w2, w3};
    long long base = (long long)qrow * NC + chunk * 4;
    *(uint4*)(cand_p + base) = o;
  }
}

// ---------- Kernel 3: finalize, ONE WAVE PER QUERY (barrier-free phases) ----------
// Wave: top-16 of 784 in-reg -> fp64 rescore (2 passes x 8 cands x 8 lanes x 32 dims)
// -> rank-based parallel top-8 -> scores/usage/gather.
__global__ __launch_bounds__(256) void finalize_kernel(const unsigned int* __restrict__ cand_p,
                                                       const double* __restrict__ q64n,
                                                       const float* __restrict__ keys,
                                                       const double* __restrict__ kinv64,
                                                       const float* __restrict__ values,
                                                       float* __restrict__ scores_out,
                                                       float* __restrict__ out_rv,
                                                       float* __restrict__ usage_out) {
  __shared__ int f8s[4][8];
  const int wv = threadIdx.x >> 6;
  const int l = threadIdx.x & 63;
  const int q = blockIdx.x * 4 + wv;

  // Phase A: wave-wide top-16 of 784 packed candidates; lane r captures winner r's key idx.
  unsigned int lv[13];
  int li[13];
#pragma unroll
  for (int s = 0; s < 13; s++) {
    int c = l + 64 * s;
    if (c < NC) {
      unsigned int p = cand_p[(long long)q * NC + c];
      lv[s] = p;
      li[s] = (c >> 2) * KCHUNK + (int)(p & 255u);
    } else { lv[s] = 0u; li[s] = 0x7fffffff; }
  }
  int myidx = 0;
#pragma unroll 1
  for (int r = 0; r < NCAND; r++) {
    unsigned int bv = 0u;
    int bi = 0x7fffffff;
#pragma unroll
    for (int s = 0; s < 13; s++)
      if (lv[s] > bv || (lv[s] == bv && li[s] < bi)) { bv = lv[s]; bi = li[s]; }
#pragma unroll
    for (int m = 32; m; m >>= 1) {
      unsigned int ov = (unsigned int)__shfl_xor((int)bv, m, 64);
      int oi = __shfl_xor(bi, m, 64);
      if (ov > bv || (ov == bv && oi < bi)) { bv = ov; bi = oi; }
    }
    if (l == r) myidx = bi;
#pragma unroll
    for (int s = 0; s < 13; s++)
      if (li[s] == bi) lv[s] = 0u;
  }

  // Phase B: fp64 rescore; pass p covers candidates p*8 + (l>>3); 8 lanes x 32 dims.
  const int sub = l & 7;
  const double* qr = &q64n[(long long)q * D + sub * 32];
  double qv[32];
#pragma unroll
  for (int t = 0; t < 32; t++) qv[t] = qr[t];
  double scp[2];
#pragma unroll 1
  for (int p = 0; p < 2; p++) {
    int cand = p * 8 + (l >> 3);
    int idx = __shfl(myidx, cand, 64);
    const float* kr = &keys[(long long)idx * D + sub * 32];
    double s = 0.0;
#pragma unroll
    for (int t = 0; t < 32; t++) s = fma(qv[t], (double)kr[t], s);
#pragma unroll
    for (int m = 4; m; m >>= 1) s += __shfl_xor(s, m, 8);
    scp[p] = s * kinv64[idx];
  }

  // Phase C: lanes 0..15 own candidate l; compute exact rank among 16 (fp64, tie: idx asc).
  double a0 = __shfl(scp[0], (l & 7) * 8, 64);
  double a1 = __shfl(scp[1], (l & 7) * 8, 64);
  double myv = (l < 8) ? a0 : a1;
  int rank = 0;
#pragma unroll
  for (int t = 0; t < NCAND; t++) {
    double tv = __shfl(myv, t, 64);
    int ti = __shfl(myidx, t, 64);
    if (tv > myv || (tv == myv && ti < myidx)) rank++;
  }
  if (l < NCAND && rank < 8) {
    scores_out[q * 8 + rank] = (float)myv;
    atomicAdd(&usage_out[myidx], 1.0f);
    f8s[wv][rank] = myidx;
  }
  __syncthreads();

  // Phase D: gather 8 x 256 values (8 lanes per row, 32 floats each)
  {
    const int row = l >> 3;
    const int c0 = sub * 32;
    int idx = f8s[wv][row];
    const float* vr = &values[(long long)idx * D + c0];
    float* orow = &out_rv[((long long)q * 8 + row) * D + c0];
#pragma unroll
    for (int t = 0; t < 8; t++)
      *(float4*)(&orow[t * 4]) = *(const float4*)(&vr[t * 4]);
  }
}

extern "C" void kernel_launch(void* const* d_in, const int* in_sizes, int n_in,
                              void* d_out, int out_size, void* d_ws, size_t ws_size,
                              hipStream_t stream) {
  (void)in_sizes; (void)n_in; (void)out_size; (void)ws_size;
  const float* query  = (const float*)d_in[0];
  const float* W      = (const float*)d_in[1];
  const float* b      = (const float*)d_in[2];
  const float* keys   = (const float*)d_in[3];
  const float* values = (const float*)d_in[4];
  const float* usage  = (const float*)d_in[5];

  float* out    = (float*)d_out;
  float* out_rv = out;                    // 2048*8*256
  float* out_sc = out + BQ * 8 * D;       // 2048*8
  float* out_us = out_sc + BQ * 8;        // 50000

  double*         q64n   = (double*)d_ws;                     // 524288 d  (4MB)
  double*         kinv64 = q64n + BQ * D;                     // 50000 d
  unsigned short* qbf    = (unsigned short*)(kinv64 + NKEYS); // 524288 us (1MB)
  unsigned short* kbf    = qbf + BQ * D;                      // 50176*256 (25.7MB)
  unsigned int*   cand_p = (unsigned int*)(kbf + (long long)NKPAD * D); // 2048*784 (6.4MB)

  // prep: 256 qnorm blocks + 12544 kprep blocks in one launch (parallel execution)
  hipLaunchKernelGGL(prep_kernel, dim3(256 + NKPAD / 4), dim3(256), 0, stream,
                     query, W, b, keys, usage, qbf, q64n, kinv64, kbf, out_us);
  // grid 3200 = 8 XCD-slots x 16 q-tiles (inner) x 25 chunk-groups (chunk >= 196 early-exits)
  hipLaunchKernelGGL(sim_mfma_kernel, dim3(3200), dim3(256), 0, stream, qbf, kbf, cand_p);
  // finalize: 512 blocks x 4 independent waves = 2048 queries
  hipLaunchKernelGGL(finalize_kernel, dim3(BQ / 4), dim3(256), 0, stream, cand_p, q64n, keys, kinv64, values, out_sc, out_rv, out_us);
}